// Round 6
// baseline (3634.929 us; speedup 1.0000x reference)
//
#include <hip/hip_runtime.h>
#include <cstdint>
#include <cstddef>

// ---- model constants ----
#define B_    16
#define S_    256
#define H_    384
#define H2_   1536
#define NH_   2
#define DH_   192
#define TOUT_ 1024
#define MEL_  80
#define L_    4

// ---- gemm epilogue flags ----
#define F_BIAS  1
#define F_RES   2
#define F_RELU  4
#define F_STF   8
#define F_STB   16
#define F_TRANS 32

typedef __attribute__((ext_vector_type(8))) short short8;
typedef __attribute__((ext_vector_type(4))) float floatx4;

typedef const __attribute__((address_space(1))) unsigned int* as1p;
typedef __attribute__((address_space(3))) unsigned int* as3p;

// async global->LDS, 16B per lane; LDS dest = wave-uniform base + lane*16
__device__ __forceinline__ void gld16(const void* g, void* l) {
  __builtin_amdgcn_global_load_lds((as1p)g, (as3p)l, 16, 0, 0);
}

// fp32 -> bf16 bits, round-to-nearest-even
__device__ __forceinline__ short f2b(float f) {
  union { float f; unsigned u; } v; v.f = f;
  unsigned r = (v.u + 0x7fffu + ((v.u >> 16) & 1u)) >> 16;
  return (short)r;
}

__device__ __forceinline__ float pe_val(int t, int i) {
  int j = i >> 1;
  float den = __expf(-9.210340371976184f * (float)(2 * j) / (float)H_);
  float ang = (float)t * den;
  return (i & 1) ? __cosf(ang) : __sinf(ang);
}

// ============ weight prep ============
__global__ __launch_bounds__(256) void wtrans_kernel(const float* __restrict__ sa,
                                                     const float* __restrict__ sb,
                                                     int na, int K, int N,
                                                     short* __restrict__ dst) {
  __shared__ float t[32][33];
  int id = blockIdx.z;
  const float* s = (id < na) ? sa + (size_t)id * K * N : sb + (size_t)(id - na) * K * N;
  short* o = dst + (size_t)id * K * N;
  int n0 = blockIdx.x * 32, k0 = blockIdx.y * 32;
  int tx = threadIdx.x & 31, ty = threadIdx.x >> 5;
#pragma unroll
  for (int i = 0; i < 4; ++i)
    t[ty + i * 8][tx] = s[(size_t)(k0 + ty + i * 8) * N + n0 + tx];
  __syncthreads();
#pragma unroll
  for (int i = 0; i < 4; ++i)
    o[(size_t)(n0 + ty + i * 8) * K + k0 + tx] = f2b(t[tx][ty + i * 8]);
}

__global__ void melpad_kernel(const float* __restrict__ w, short* __restrict__ dst) {
  int i = blockIdx.x * 256 + threadIdx.x;     // 128*384
  int n = i / H_, k = i - n * H_;
  dst[i] = (n < MEL_) ? f2b(w[(size_t)k * MEL_ + n]) : (short)0;
}

// ============ embedding + posenc ============
__global__ void embed_kernel(const int* __restrict__ tokens, const float* __restrict__ emb,
                             float* __restrict__ xf, short* __restrict__ xb) {
  int bs = blockIdx.x;
  int t  = bs & (S_ - 1);
  int tok = tokens[bs];
  const float* e = emb + (size_t)tok * H_;
  float* of = xf + (size_t)bs * H_;
  short* ob = xb + (size_t)bs * H_;
  for (int i = threadIdx.x; i < H_; i += blockDim.x) {
    float v = e[i] * 19.595917942265423f + pe_val(t, i);
    of[i] = v; ob[i] = f2b(v);
  }
}

// ============ bf16 MFMA GEMM v3 ============
// C[M,N] = sum_tap shift(A)[M,K] @ W[tap][K,N]; Wt is [ntaps][N][K] bf16.
// B fragments read DIRECTLY from global (weights are L2-resident; coalesced
// 16-row x 64B pattern). Only A is LDS-staged, double-buffered: stage(k+1)
// at iter start, compute(k), one barrier per iter -> the vmcnt drain at the
// barrier waits on a transfer issued a whole compute-phase earlier.
template<int NTAPS, int MTW>
__global__ __launch_bounds__(256) void mfma_gemm(
    const short* __restrict__ A, const short* __restrict__ Wt,
    const float* __restrict__ bias, const float* __restrict__ res,
    float* __restrict__ Cf, short* __restrict__ Cb, const short* __restrict__ zbuf,
    int M, int N, int Kd, int T, int Nout, int flags)
{
  constexpr int TM   = MTW * 32;                 // 128 or 64 rows
  constexpr int HB   = NTAPS / 2;
  constexpr int RA   = TM + NTAPS - 1;
  constexpr int RNDA = (RA + 63) / 64;
  __shared__ __align__(16) short As[2][RA * 32];
  const int tid = threadIdx.x;
  const int wave = tid >> 6, lane = tid & 63, quad = lane >> 4, lm = lane & 15;
  const int bm = blockIdx.y * TM, bn = blockIdx.x * 128;
  const int wm = (wave >> 1) * (TM / 2), wn = (wave & 1) * 64;
  const int b0 = bm / T, t0 = bm - b0 * T;       // TM | T, block never crosses batch
  const int NK = Kd >> 5;
  floatx4 acc[MTW][4] = {};

  auto stageA = [&](int k0, int bi) {
#pragma unroll
    for (int jj = 0; jj < RNDA; ++jj) {
      int r0 = (jj == RNDA - 1) ? (RA - 64) : jj * 64;
      int r = r0 + (tid >> 2);
      int t = t0 - HB + r;
      const short* g = (t >= 0 && t < T)
          ? (A + (size_t)(b0 * T + t) * Kd + k0 + (tid & 3) * 8) : zbuf;
      gld16(g, &As[bi][r0 * 32] + wave * 512);
    }
  };

  stageA(0, 0);
  __syncthreads();

  for (int i = 0; i < NK; ++i) {
    const int k0 = i << 5, bi = i & 1;
    if (i + 1 < NK) stageA(k0 + 32, bi ^ 1);     // async prefetch into other buffer
    // direct B loads (independent, vmcnt-pipelined with the MFMAs below)
    short8 bfr[NTAPS][4];
#pragma unroll
    for (int tap = 0; tap < NTAPS; ++tap)
#pragma unroll
      for (int nt = 0; nt < 4; ++nt)
        bfr[tap][nt] = *(const short8*)(Wt + ((size_t)tap * N + bn + wn + nt * 16 + lm) * Kd
                                        + k0 + quad * 8);
#pragma unroll
    for (int tap = 0; tap < NTAPS; ++tap) {
      short8 af[MTW];
#pragma unroll
      for (int mt = 0; mt < MTW; ++mt)
        af[mt] = *(const short8*)(&As[bi][(wm + mt * 16 + lm + tap) * 32 + quad * 8]);
#pragma unroll
      for (int mt = 0; mt < MTW; ++mt)
#pragma unroll
        for (int nt = 0; nt < 4; ++nt)
          acc[mt][nt] = __builtin_amdgcn_mfma_f32_16x16x32_bf16(af[mt], bfr[tap][nt],
                                                                acc[mt][nt], 0, 0, 0);
    }
    __syncthreads();   // guards buffer reuse; drains the early-issued prefetch
  }

#pragma unroll
  for (int mt = 0; mt < MTW; ++mt) {
#pragma unroll
    for (int r2 = 0; r2 < 4; ++r2) {
      int gm = bm + wm + mt * 16 + quad * 4 + r2;
#pragma unroll
      for (int nt = 0; nt < 4; ++nt) {
        int gn = bn + wn + nt * 16 + lm;
        float v = acc[mt][nt][r2];
        if (flags & F_TRANS) {
          if (gn < Nout) {
            if (flags & F_BIAS) v += bias[gn];
            int bb = gm / T, tt = gm - bb * T;
            Cf[((size_t)bb * Nout + gn) * T + tt] = v;
          }
          continue;
        }
        if (flags & F_BIAS) v += bias[gn];
        size_t idx = (size_t)gm * N + gn;
        if (flags & F_RES) v += res[idx];
        if (flags & F_RELU) v = fmaxf(v, 0.f);
        if (flags & F_STF) Cf[idx] = v;
        if (flags & F_STB) Cb[idx] = f2b(v);
      }
    }
  }
}

// ============ V transpose: QKV cols 768..1151 -> Vt[b][h][d][T] ============
__global__ __launch_bounds__(256) void vtrans_kernel(const short* __restrict__ qkv,
                                                     short* __restrict__ vt, int T) {
  __shared__ short tile[32][34];
  int b = blockIdx.z, d0 = blockIdx.y * 32, t0 = blockIdx.x * 32;
  int tx = threadIdx.x & 31, ty = threadIdx.x >> 5;
#pragma unroll
  for (int i = 0; i < 4; ++i)
    tile[ty + i * 8][tx] = qkv[(size_t)(b * T + t0 + ty + i * 8) * 1152 + 768 + d0 + tx];
  __syncthreads();
  int h = (d0 >= DH_) ? 1 : 0;
  int dd0 = d0 - h * DH_;
#pragma unroll
  for (int i = 0; i < 4; ++i)
    vt[((size_t)((b * NH_ + h) * DH_) + dd0 + ty + i * 8) * T + t0 + tx] = tile[tx][ty + i * 8];
}

// ============ flash MFMA attention: block = (b, h, 64-query tile) ============
template<int T>
__global__ __launch_bounds__(256) void attn_flash(const short* __restrict__ qkv,
                                                  const short* __restrict__ vt,
                                                  short* __restrict__ o)
{
  constexpr int NKT = T / 32;
  __shared__ __align__(16) short Kb[2][6144];
  __shared__ __align__(16) short Vb[2][6144];
  __shared__ __align__(16) short Pb[4][16 * 40];
  const int tid = threadIdx.x;
  const int wave = tid >> 6, lane = tid & 63, quad = lane >> 4, lm = lane & 15;
  const int id = blockIdx.x;
  const int bh = id & 31, h = bh & 1, b = bh >> 1;
  const int q0 = (id >> 5) * 64;
  const short* qb = qkv + (size_t)b * T * 1152 + h * DH_;
  const short* kb = qb + 384;
  const short* vb = vt + (size_t)(b * NH_ + h) * DH_ * T;

  short8 qf[6];
  {
    const short* qrow = qb + (size_t)(q0 + wave * 16 + lm) * 1152 + quad * 8;
#pragma unroll
    for (int c6 = 0; c6 < 6; ++c6) qf[c6] = *(const short8*)(qrow + c6 * 32);
  }

  auto stage = [&](int kc, int bi) {
#pragma unroll
    for (int j = 0; j < 3; ++j) {
      int g = j * 256 + tid;
      int lmg = g & 15, qg = (g >> 4) & 3, ct = g >> 6;
      int c6 = ct % 6, kt = ct / 6;
      gld16(kb + (size_t)(kc * 32 + kt * 16 + lmg) * 1152 + c6 * 32 + qg * 8,
            &Kb[bi][j * 2048 + wave * 512]);
    }
#pragma unroll
    for (int j = 0; j < 3; ++j) {
      int g = j * 256 + tid;
      int lmg = g & 15, qg = (g >> 4) & 3, dt = g >> 6;
      gld16(vb + (size_t)(dt * 16 + lmg) * T + kc * 32 + qg * 8,
            &Vb[bi][j * 2048 + wave * 512]);
    }
  };

  float m_r[4] = {-1e30f, -1e30f, -1e30f, -1e30f};
  float l_r[4] = {0.f, 0.f, 0.f, 0.f};
  floatx4 oacc[12] = {};

  stage(0, 0);
  __syncthreads();

  for (int kc = 0; kc < NKT; ++kc) {
    const int cur = kc & 1;
    if (kc + 1 < NKT) stage(kc + 1, cur ^ 1);

    floatx4 s0 = {0.f, 0.f, 0.f, 0.f}, s1 = {0.f, 0.f, 0.f, 0.f};
#pragma unroll
    for (int c6 = 0; c6 < 6; ++c6) {
      short8 k0f = *(const short8*)(&Kb[cur][(c6 * 64 + quad * 16 + lm) * 8]);
      short8 k1f = *(const short8*)(&Kb[cur][((6 + c6) * 64 + quad * 16 + lm) * 8]);
      s0 = __builtin_amdgcn_mfma_f32_16x16x32_bf16(qf[c6], k0f, s0, 0, 0, 0);
      s1 = __builtin_amdgcn_mfma_f32_16x16x32_bf16(qf[c6], k1f, s1, 0, 0, 0);
    }

    float al[4];
#pragma unroll
    for (int r2 = 0; r2 < 4; ++r2) {
      float a = s0[r2] * 0.07216878364870323f;
      float c = s1[r2] * 0.07216878364870323f;
      float t = fmaxf(a, c);
#pragma unroll
      for (int off = 1; off < 16; off <<= 1) t = fmaxf(t, __shfl_xor(t, off, 64));
      float mn = fmaxf(m_r[r2], t);
      al[r2] = __expf(m_r[r2] - mn);
      m_r[r2] = mn;
      float e0 = __expf(a - mn), e1 = __expf(c - mn);
      l_r[r2] = al[r2] * l_r[r2] + e0 + e1;
      Pb[wave][(quad * 4 + r2) * 40 + lm]      = f2b(e0);
      Pb[wave][(quad * 4 + r2) * 40 + 16 + lm] = f2b(e1);
    }
#pragma unroll
    for (int dt = 0; dt < 12; ++dt) {
#pragma unroll
      for (int r2 = 0; r2 < 4; ++r2) oacc[dt][r2] *= al[r2];
    }

    short8 pf = *(const short8*)(&Pb[wave][lm * 40 + quad * 8]);
#pragma unroll
    for (int dt = 0; dt < 12; ++dt) {
      short8 vf = *(const short8*)(&Vb[cur][(dt * 64 + quad * 16 + lm) * 8]);
      oacc[dt] = __builtin_amdgcn_mfma_f32_16x16x32_bf16(pf, vf, oacc[dt], 0, 0, 0);
    }
    __syncthreads();
  }

#pragma unroll
  for (int r2 = 0; r2 < 4; ++r2) {
#pragma unroll
    for (int off = 1; off < 16; off <<= 1) l_r[r2] += __shfl_xor(l_r[r2], off, 64);
    l_r[r2] = 1.f / l_r[r2];
  }
  short* orow = o + (size_t)(b * T + q0 + wave * 16) * H_ + h * DH_;
#pragma unroll
  for (int dt = 0; dt < 12; ++dt) {
#pragma unroll
    for (int r2 = 0; r2 < 4; ++r2)
      orow[(size_t)(quad * 4 + r2) * H_ + dt * 16 + lm] = f2b(oacc[dt][r2] * l_r[r2]);
  }
}

// ============ LayerNorm (H=384), wave per row ============
__global__ __launch_bounds__(256) void ln_kernel(const float* __restrict__ X,
                                                 const float* __restrict__ sb,
                                                 float* __restrict__ Yf,
                                                 short* __restrict__ Yb, int M)
{
  int row  = blockIdx.x * 4 + (threadIdx.x >> 6);
  int lane = threadIdx.x & 63;
  const float* x = X + (size_t)row * H_;
  float v[6]; float s = 0.f, ss = 0.f;
#pragma unroll
  for (int i = 0; i < 6; ++i) { v[i] = x[lane + i * 64]; s += v[i]; ss += v[i] * v[i]; }
#pragma unroll
  for (int o = 32; o; o >>= 1) { s += __shfl_down(s, o, 64); ss += __shfl_down(ss, o, 64); }
  s = __shfl(s, 0, 64); ss = __shfl(ss, 0, 64);
  float mean = s * (1.0f / H_);
  float var  = ss * (1.0f / H_) - mean * mean;
  float r = rsqrtf(var + 1e-5f);
  float* yf = Yf + (size_t)row * H_;
#pragma unroll
  for (int i = 0; i < 6; ++i) {
    int c = lane + i * 64;
    float y = (v[i] - mean) * r * sb[c] + sb[H_ + c];
    yf[c] = y;
    if (Yb) Yb[(size_t)row * H_ + c] = f2b(y);
  }
}

// ============ length-pred GEMV ============
__global__ void gemv_kernel(const float* __restrict__ A, const float* __restrict__ w,
                            const float* __restrict__ bflt, float* __restrict__ out, int M)
{
  int row  = blockIdx.x * 4 + (threadIdx.x >> 6);
  int lane = threadIdx.x & 63;
  const float* a = A + (size_t)row * H_;
  float s = 0.f;
#pragma unroll
  for (int i = 0; i < 6; ++i) s += a[lane + i * 64] * w[lane + i * 64];
#pragma unroll
  for (int o = 32; o; o >>= 1) s += __shfl_down(s, o, 64);
  if (lane == 0) out[row] = s + bflt[0];
}

__global__ void cumsum_kernel(const int* __restrict__ al, int* __restrict__ cum) {
  int b = threadIdx.x;
  if (b < B_) {
    int acc = 0;
    for (int s = 0; s < S_; ++s) { acc += al[b * S_ + s]; cum[b * S_ + s] = acc; }
  }
}

__global__ void expand_kernel(const float* __restrict__ xe, const int* __restrict__ cum,
                              float* __restrict__ yf, short* __restrict__ yb) {
  int t = blockIdx.x, b = blockIdx.y;
  const int* c = cum + b * S_;
  int lo = 0, hi = S_;
  while (lo < hi) { int mid = (lo + hi) >> 1; if (c[mid] <= t) lo = mid + 1; else hi = mid; }
  int idx = lo < S_ ? lo : S_ - 1;
  bool valid = t < c[S_ - 1];
  const float* src = xe + ((size_t)b * S_ + idx) * H_;
  float* df = yf + ((size_t)b * TOUT_ + t) * H_;
  short* db = yb + ((size_t)b * TOUT_ + t) * H_;
  for (int i = threadIdx.x; i < H_; i += blockDim.x) {
    float v = (valid ? src[i] : 0.f) + pe_val(t, i);
    df[i] = v; db[i] = f2b(v);
  }
}

// ================= host orchestration =================
// mtw: 4 -> 128-row tile (wide-N GEMMs), 2 -> 64-row tile (N<=512 GEMMs)
static inline void gemm(const short* A, const short* Wt, const float* bias, const float* res,
                        float* Cf, short* Cb, const short* zbuf, int M, int N, int Kd, int T,
                        int ntaps, int mtw, int Nout, int flags, hipStream_t st) {
  int tm = mtw * 32;
  dim3 g((N + 127) / 128, M / tm);
  if (ntaps == 3) {
    if (mtw == 4)
      mfma_gemm<3,4><<<g, 256, 0, st>>>(A, Wt, bias, res, Cf, Cb, zbuf, M, N, Kd, T, Nout, flags);
    else
      mfma_gemm<3,2><<<g, 256, 0, st>>>(A, Wt, bias, res, Cf, Cb, zbuf, M, N, Kd, T, Nout, flags);
  } else {
    if (mtw == 4)
      mfma_gemm<1,4><<<g, 256, 0, st>>>(A, Wt, bias, res, Cf, Cb, zbuf, M, N, Kd, T, Nout, flags);
    else
      mfma_gemm<1,2><<<g, 256, 0, st>>>(A, Wt, bias, res, Cf, Cb, zbuf, M, N, Kd, T, Nout, flags);
  }
}

struct LayerW { const short *attn, *c1, *c2; const float *ab, *c1b, *c2b, *ln; };

static void fft_block(float* x, short* xb, short* qkvb, short* ob, short* vtb, short* h2b,
                      const short* zbuf, const LayerW& w, int T, hipStream_t st)
{
  int M = B_ * T;
  const size_t msz = (size_t)H_ * H_;
  gemm(xb, w.attn, w.ab, nullptr, nullptr, qkvb, zbuf, M, 1152, H_, T, 1, 4, 0,
       F_BIAS | F_STB, st);
  vtrans_kernel<<<dim3(T / 32, 12, B_), 256, 0, st>>>(qkvb, vtb, T);
  if (T == 256) attn_flash<256><<<dim3((256 / 64) * 32), 256, 0, st>>>(qkvb, vtb, ob);
  else          attn_flash<1024><<<dim3((1024 / 64) * 32), 256, 0, st>>>(qkvb, vtb, ob);
  gemm(ob, w.attn + 3 * msz, w.ab + 3 * H_, x, x, nullptr, zbuf, M, H_, H_, T, 1, 2, 0,
       F_BIAS | F_RES | F_STF, st);
  ln_kernel<<<M / 4, 256, 0, st>>>(x, w.ln, x, xb, M);
  gemm(xb, w.c1, w.c1b, nullptr, nullptr, h2b, zbuf, M, H2_, H_, T, 3, 4, 0,
       F_BIAS | F_RELU | F_STB, st);
  gemm(h2b, w.c2, w.c2b, x, x, nullptr, zbuf, M, H_, H2_, T, 3, 2, 0,
       F_BIAS | F_RES | F_STF, st);
  ln_kernel<<<M / 4, 256, 0, st>>>(x, w.ln + 2 * H_, x, xb, M);
}

extern "C" void kernel_launch(void* const* d_in, const int* in_sizes, int n_in,
                              void* d_out, int out_size, void* d_ws, size_t ws_size,
                              hipStream_t stream)
{
  (void)in_sizes; (void)n_in; (void)out_size; (void)ws_size;
  const int*   tokens      = (const int*)d_in[0];
  const int*   alignes     = (const int*)d_in[1];
  const float* tok_emb     = (const float*)d_in[2];
  const float* enc_attn_w  = (const float*)d_in[3];
  const float* enc_attn_b  = (const float*)d_in[4];
  const float* enc_conv1_w = (const float*)d_in[5];
  const float* enc_conv1_b = (const float*)d_in[6];
  const float* enc_conv2_w = (const float*)d_in[7];
  const float* enc_conv2_b = (const float*)d_in[8];
  const float* enc_ln      = (const float*)d_in[9];
  const float* dec_attn_w  = (const float*)d_in[10];
  const float* dec_attn_b  = (const float*)d_in[11];
  const float* dec_conv1_w = (const float*)d_in[12];
  const float* dec_conv1_b = (const float*)d_in[13];
  const float* dec_conv2_w = (const float*)d_in[14];
  const float* dec_conv2_b = (const float*)d_in[15];
  const float* dec_ln      = (const float*)d_in[16];
  const float* al_c1w      = (const float*)d_in[17];
  const float* al_c1b      = (const float*)d_in[18];
  const float* al_c2w      = (const float*)d_in[19];
  const float* al_c2b      = (const float*)d_in[20];
  const float* al_ln       = (const float*)d_in[21];
  const float* al_lin_w    = (const float*)d_in[22];
  const float* al_lin_b    = (const float*)d_in[23];
  const float* dec_lin_w   = (const float*)d_in[24];
  const float* dec_lin_b   = (const float*)d_in[25];

  char* base = (char*)d_ws;
  size_t off = 0;
  auto alloc = [&](size_t bytes) -> char* {
    char* p = base + off;
    off += (bytes + 255) & ~(size_t)255;
    return p;
  };
  const size_t ME = (size_t)B_ * S_;      // 4096
  const size_t MD = (size_t)B_ * TOUT_;   // 16384
  float* xe   = (float*)alloc(ME * H_ * 4);
  short* xeb  = (short*)alloc(ME * H_ * 2);
  float* xd   = (float*)alloc(MD * H_ * 4);
  short* xdb  = (short*)alloc(MD * H_ * 2);
  short* qkvb = (short*)alloc(MD * 1152 * 2);
  short* ob   = (short*)alloc(MD * H_ * 2);
  short* h2b  = (short*)alloc(MD * H2_ * 2);     // first 12.6MB doubles as vtb
  short* vtb  = h2b;
  short* wAt  = (short*)alloc((size_t)32 * H_ * H_ * 2);
  short* wAl  = (short*)alloc((size_t)6 * H_ * H_ * 2);
  short* wC1  = (short*)alloc((size_t)24 * H_ * H2_ * 2);
  short* wC2  = (short*)alloc((size_t)24 * H_ * H2_ * 2);
  short* wMel = (short*)alloc((size_t)128 * H_ * 2);
  int*   cum  = (int*)alloc(ME * 4);
  short* zbuf = (short*)alloc(256);
  float* alf  = xd;                // aligner scratch (xd/xdb free until expand)
  short* alb  = xdb;

  float* mel_out = (float*)d_out;
  float* len_out = mel_out + (size_t)B_ * MEL_ * TOUT_;

  hipMemsetAsync(zbuf, 0, 256, stream);

  // ---- weight prep ----
  wtrans_kernel<<<dim3(12, 12, 32), 256, 0, stream>>>(enc_attn_w, dec_attn_w, 16, H_, H_, wAt);
  wtrans_kernel<<<dim3(12, 12, 6),  256, 0, stream>>>(al_c1w, al_c2w, 3, H_, H_, wAl);
  wtrans_kernel<<<dim3(48, 12, 24), 256, 0, stream>>>(enc_conv1_w, dec_conv1_w, 12, H_, H2_, wC1);
  wtrans_kernel<<<dim3(12, 48, 24), 256, 0, stream>>>(enc_conv2_w, dec_conv2_w, 12, H2_, H_, wC2);
  melpad_kernel<<<dim3(128 * H_ / 256), 256, 0, stream>>>(dec_lin_w, wMel);

  // ---- encoder ----
  embed_kernel<<<dim3(B_ * S_), 128, 0, stream>>>(tokens, tok_emb, xe, xeb);
  for (int i = 0; i < L_; ++i) {
    LayerW w;
    w.attn = wAt + (size_t)i * 4 * H_ * H_;
    w.c1   = wC1 + (size_t)i * 3 * H_ * H2_;
    w.c2   = wC2 + (size_t)i * 3 * H_ * H2_;
    w.ab   = enc_attn_b + (size_t)i * 4 * H_;
    w.c1b  = enc_conv1_b + (size_t)i * H2_;
    w.c2b  = enc_conv2_b + (size_t)i * H_;
    w.ln   = enc_ln + (size_t)i * 4 * H_;
    fft_block(xe, xeb, qkvb, ob, vtb, h2b, zbuf, w, S_, stream);
  }

  // ---- aligner ----
  {
    int Ma = B_ * S_;
    gemm(xeb, wAl, al_c1b, nullptr, alf, nullptr, zbuf, Ma, H_, H_, S_, 3, 2, 0,
         F_BIAS | F_RELU | F_STF, stream);
    ln_kernel<<<Ma / 4, 256, 0, stream>>>(alf, al_ln, alf, alb, Ma);
    gemm(alb, wAl + (size_t)3 * H_ * H_, al_c2b, nullptr, alf, nullptr, zbuf, Ma, H_, H_, S_,
         3, 2, 0, F_BIAS | F_RELU | F_STF, stream);
    ln_kernel<<<Ma / 4, 256, 0, stream>>>(alf, al_ln + 2 * H_, alf, (short*)nullptr, Ma);
    gemv_kernel<<<Ma / 4, 256, 0, stream>>>(alf, al_lin_w, al_lin_b, len_out, Ma);
  }

  // ---- length regulator ----
  cumsum_kernel<<<1, 64, 0, stream>>>(alignes, cum);
  expand_kernel<<<dim3(TOUT_, B_), 128, 0, stream>>>(xe, cum, xd, xdb);

  // ---- decoder ----
  for (int i = 0; i < L_; ++i) {
    LayerW w;
    w.attn = wAt + (size_t)(16 + i * 4) * H_ * H_;
    w.c1   = wC1 + (size_t)(12 + i * 3) * H_ * H2_;
    w.c2   = wC2 + (size_t)(12 + i * 3) * H_ * H2_;
    w.ab   = dec_attn_b + (size_t)i * 4 * H_;
    w.c1b  = dec_conv1_b + (size_t)i * H2_;
    w.c2b  = dec_conv2_b + (size_t)i * H_;
    w.ln   = dec_ln + (size_t)i * 4 * H_;
    fft_block(xd, xdb, qkvb, ob, vtb, h2b, zbuf, w, TOUT_, stream);
  }

  // ---- final mel projection, transposed write [B, MEL, TOUT] ----
  gemm(xdb, wMel, dec_lin_b, nullptr, mel_out, nullptr, zbuf, B_ * TOUT_, 128, H_, TOUT_,
       1, 2, MEL_, F_BIAS | F_TRANS, stream);
}

// Round 7
// 2694.542 us; speedup vs baseline: 1.3490x; 1.3490x over previous
//
#include <hip/hip_runtime.h>
#include <cstdint>
#include <cstddef>

// ---- model constants ----
#define B_    16
#define S_    256
#define H_    384
#define H2_   1536
#define NH_   2
#define DH_   192
#define TOUT_ 1024
#define MEL_  80
#define L_    4

// ---- gemm epilogue flags ----
#define F_BIAS  1
#define F_RES   2
#define F_RELU  4
#define F_STF   8
#define F_STB   16
#define F_TRANS 32

typedef __attribute__((ext_vector_type(8))) short short8;
typedef __attribute__((ext_vector_type(4))) float floatx4;

typedef const __attribute__((address_space(1))) unsigned int* as1p;
typedef __attribute__((address_space(3))) unsigned int* as3p;

// async global->LDS, 16B per lane; LDS dest = wave-uniform base + lane*16
__device__ __forceinline__ void gld16(const void* g, void* l) {
  __builtin_amdgcn_global_load_lds((as1p)g, (as3p)l, 16, 0, 0);
}

// fp32 -> bf16 bits, round-to-nearest-even
__device__ __forceinline__ short f2b(float f) {
  union { float f; unsigned u; } v; v.f = f;
  unsigned r = (v.u + 0x7fffu + ((v.u >> 16) & 1u)) >> 16;
  return (short)r;
}

__device__ __forceinline__ float pe_val(int t, int i) {
  int j = i >> 1;
  float den = __expf(-9.210340371976184f * (float)(2 * j) / (float)H_);
  float ang = (float)t * den;
  return (i & 1) ? __cosf(ang) : __sinf(ang);
}

// ============ weight prep ============
__global__ __launch_bounds__(256) void wtrans_kernel(const float* __restrict__ sa,
                                                     const float* __restrict__ sb,
                                                     int na, int K, int N,
                                                     short* __restrict__ dst) {
  __shared__ float t[32][33];
  int id = blockIdx.z;
  const float* s = (id < na) ? sa + (size_t)id * K * N : sb + (size_t)(id - na) * K * N;
  short* o = dst + (size_t)id * K * N;
  int n0 = blockIdx.x * 32, k0 = blockIdx.y * 32;
  int tx = threadIdx.x & 31, ty = threadIdx.x >> 5;
#pragma unroll
  for (int i = 0; i < 4; ++i)
    t[ty + i * 8][tx] = s[(size_t)(k0 + ty + i * 8) * N + n0 + tx];
  __syncthreads();
#pragma unroll
  for (int i = 0; i < 4; ++i)
    o[(size_t)(n0 + ty + i * 8) * K + k0 + tx] = f2b(t[tx][ty + i * 8]);
}

__global__ void melpad_kernel(const float* __restrict__ w, short* __restrict__ dst) {
  int i = blockIdx.x * 256 + threadIdx.x;     // 128*384
  int n = i / H_, k = i - n * H_;
  dst[i] = (n < MEL_) ? f2b(w[(size_t)k * MEL_ + n]) : (short)0;
}

// ============ embedding + posenc ============
__global__ void embed_kernel(const int* __restrict__ tokens, const float* __restrict__ emb,
                             float* __restrict__ xf, short* __restrict__ xb) {
  int bs = blockIdx.x;
  int t  = bs & (S_ - 1);
  int tok = tokens[bs];
  const float* e = emb + (size_t)tok * H_;
  float* of = xf + (size_t)bs * H_;
  short* ob = xb + (size_t)bs * H_;
  for (int i = threadIdx.x; i < H_; i += blockDim.x) {
    float v = e[i] * 19.595917942265423f + pe_val(t, i);
    of[i] = v; ob[i] = f2b(v);
  }
}

// ============ bf16 MFMA GEMM (r4 structure: A+B staged via global_load_lds) ============
// C[M,N] = sum_tap shift(A)[M,K] @ W[tap][K,N]; Wt is [ntaps][N][K] bf16.
// MTW = 16-row m-subtiles per wave: 4 -> 128-row tile (wide-N), 2 -> 64-row
// tile (N<=512: quadruples grid -> restores block-level latency overlap).
template<int NTAPS, int MTW>
__global__ __launch_bounds__(256) void mfma_gemm(
    const short* __restrict__ A, const short* __restrict__ Wt,
    const float* __restrict__ bias, const float* __restrict__ res,
    float* __restrict__ Cf, short* __restrict__ Cb, const short* __restrict__ zbuf,
    int M, int N, int Kd, int T, int Nout, int flags)
{
  constexpr int TM   = MTW * 32;                 // 128 or 64 rows
  constexpr int HB   = NTAPS / 2;
  constexpr int RA   = TM + NTAPS - 1;
  constexpr int RNDA = (RA + 63) / 64;
  __shared__ __align__(16) short As[RA * 32];
  __shared__ __align__(16) short Bs[NTAPS * 128 * 32];
  const int tid = threadIdx.x;
  const int wave = tid >> 6, lane = tid & 63, quad = lane >> 4, lm = lane & 15;
  const int bm = blockIdx.y * TM, bn = blockIdx.x * 128;
  const int wm = (wave >> 1) * (TM / 2), wn = (wave & 1) * 64;
  const int b0 = bm / T, t0 = bm - b0 * T;       // TM | T, block never crosses batch
  floatx4 acc[MTW][4] = {};

  for (int k0 = 0; k0 < Kd; k0 += 32) {
#pragma unroll
    for (int jj = 0; jj < RNDA; ++jj) {
      int r0 = (jj == RNDA - 1) ? (RA - 64) : jj * 64;
      int r = r0 + (tid >> 2);
      int t = t0 - HB + r;
      const short* g = (t >= 0 && t < T)
          ? (A + (size_t)(b0 * T + t) * Kd + k0 + (tid & 3) * 8) : zbuf;
      gld16(g, As + r0 * 32 + wave * 512);
    }
#pragma unroll
    for (int jj = 0; jj < 2 * NTAPS; ++jj) {
      int gi = jj * 256 + tid;
      int tap = gi >> 9, rr = (gi >> 2) & 127, ch = gi & 3;
      const short* g = Wt + ((size_t)tap * N + bn + rr) * Kd + k0 + ch * 8;
      gld16(g, Bs + jj * 2048 + wave * 512);
    }
    __syncthreads();
#pragma unroll
    for (int tap = 0; tap < NTAPS; ++tap) {
      short8 af[MTW], bfr[4];
#pragma unroll
      for (int mt = 0; mt < MTW; ++mt)
        af[mt] = *(const short8*)(&As[(wm + mt * 16 + lm + tap) * 32 + quad * 8]);
#pragma unroll
      for (int nt = 0; nt < 4; ++nt)
        bfr[nt] = *(const short8*)(&Bs[tap * 4096 + (wn + nt * 16 + lm) * 32 + quad * 8]);
#pragma unroll
      for (int mt = 0; mt < MTW; ++mt)
#pragma unroll
        for (int nt = 0; nt < 4; ++nt)
          acc[mt][nt] = __builtin_amdgcn_mfma_f32_16x16x32_bf16(af[mt], bfr[nt],
                                                                acc[mt][nt], 0, 0, 0);
    }
    __syncthreads();
  }

#pragma unroll
  for (int mt = 0; mt < MTW; ++mt) {
#pragma unroll
    for (int r2 = 0; r2 < 4; ++r2) {
      int gm = bm + wm + mt * 16 + quad * 4 + r2;
#pragma unroll
      for (int nt = 0; nt < 4; ++nt) {
        int gn = bn + wn + nt * 16 + lm;
        float v = acc[mt][nt][r2];
        if (flags & F_TRANS) {
          if (gn < Nout) {
            if (flags & F_BIAS) v += bias[gn];
            int bb = gm / T, tt = gm - bb * T;
            Cf[((size_t)bb * Nout + gn) * T + tt] = v;
          }
          continue;
        }
        if (flags & F_BIAS) v += bias[gn];
        size_t idx = (size_t)gm * N + gn;
        if (flags & F_RES) v += res[idx];
        if (flags & F_RELU) v = fmaxf(v, 0.f);
        if (flags & F_STF) Cf[idx] = v;
        if (flags & F_STB) Cb[idx] = f2b(v);
      }
    }
  }
}

// ============ V transpose: QKV cols 768..1151 -> Vt[b][h][d][T] ============
__global__ __launch_bounds__(256) void vtrans_kernel(const short* __restrict__ qkv,
                                                     short* __restrict__ vt, int T) {
  __shared__ short tile[32][34];
  int b = blockIdx.z, d0 = blockIdx.y * 32, t0 = blockIdx.x * 32;
  int tx = threadIdx.x & 31, ty = threadIdx.x >> 5;
#pragma unroll
  for (int i = 0; i < 4; ++i)
    tile[ty + i * 8][tx] = qkv[(size_t)(b * T + t0 + ty + i * 8) * 1152 + 768 + d0 + tx];
  __syncthreads();
  int h = (d0 >= DH_) ? 1 : 0;
  int dd0 = d0 - h * DH_;
#pragma unroll
  for (int i = 0; i < 4; ++i)
    vt[((size_t)((b * NH_ + h) * DH_) + dd0 + ty + i * 8) * T + t0 + tx] = tile[tx][ty + i * 8];
}

// ============ flash MFMA attention: block = (b, h, 64-query tile) ============
template<int T>
__global__ __launch_bounds__(256) void attn_flash(const short* __restrict__ qkv,
                                                  const short* __restrict__ vt,
                                                  short* __restrict__ o)
{
  constexpr int NKT = T / 32;
  __shared__ __align__(16) short Kb[2][6144];
  __shared__ __align__(16) short Vb[2][6144];
  __shared__ __align__(16) short Pb[4][16 * 40];
  const int tid = threadIdx.x;
  const int wave = tid >> 6, lane = tid & 63, quad = lane >> 4, lm = lane & 15;
  const int id = blockIdx.x;
  const int bh = id & 31, h = bh & 1, b = bh >> 1;
  const int q0 = (id >> 5) * 64;
  const short* qb = qkv + (size_t)b * T * 1152 + h * DH_;
  const short* kb = qb + 384;
  const short* vb = vt + (size_t)(b * NH_ + h) * DH_ * T;

  short8 qf[6];
  {
    const short* qrow = qb + (size_t)(q0 + wave * 16 + lm) * 1152 + quad * 8;
#pragma unroll
    for (int c6 = 0; c6 < 6; ++c6) qf[c6] = *(const short8*)(qrow + c6 * 32);
  }

  auto stage = [&](int kc, int bi) {
#pragma unroll
    for (int j = 0; j < 3; ++j) {
      int g = j * 256 + tid;
      int lmg = g & 15, qg = (g >> 4) & 3, ct = g >> 6;
      int c6 = ct % 6, kt = ct / 6;
      gld16(kb + (size_t)(kc * 32 + kt * 16 + lmg) * 1152 + c6 * 32 + qg * 8,
            &Kb[bi][j * 2048 + wave * 512]);
    }
#pragma unroll
    for (int j = 0; j < 3; ++j) {
      int g = j * 256 + tid;
      int lmg = g & 15, qg = (g >> 4) & 3, dt = g >> 6;
      gld16(vb + (size_t)(dt * 16 + lmg) * T + kc * 32 + qg * 8,
            &Vb[bi][j * 2048 + wave * 512]);
    }
  };

  float m_r[4] = {-1e30f, -1e30f, -1e30f, -1e30f};
  float l_r[4] = {0.f, 0.f, 0.f, 0.f};
  floatx4 oacc[12] = {};

  stage(0, 0);
  __syncthreads();

  for (int kc = 0; kc < NKT; ++kc) {
    const int cur = kc & 1;
    if (kc + 1 < NKT) stage(kc + 1, cur ^ 1);

    floatx4 s0 = {0.f, 0.f, 0.f, 0.f}, s1 = {0.f, 0.f, 0.f, 0.f};
#pragma unroll
    for (int c6 = 0; c6 < 6; ++c6) {
      short8 k0f = *(const short8*)(&Kb[cur][(c6 * 64 + quad * 16 + lm) * 8]);
      short8 k1f = *(const short8*)(&Kb[cur][((6 + c6) * 64 + quad * 16 + lm) * 8]);
      s0 = __builtin_amdgcn_mfma_f32_16x16x32_bf16(qf[c6], k0f, s0, 0, 0, 0);
      s1 = __builtin_amdgcn_mfma_f32_16x16x32_bf16(qf[c6], k1f, s1, 0, 0, 0);
    }

    float al[4];
#pragma unroll
    for (int r2 = 0; r2 < 4; ++r2) {
      float a = s0[r2] * 0.07216878364870323f;
      float c = s1[r2] * 0.07216878364870323f;
      float t = fmaxf(a, c);
#pragma unroll
      for (int off = 1; off < 16; off <<= 1) t = fmaxf(t, __shfl_xor(t, off, 64));
      float mn = fmaxf(m_r[r2], t);
      al[r2] = __expf(m_r[r2] - mn);
      m_r[r2] = mn;
      float e0 = __expf(a - mn), e1 = __expf(c - mn);
      l_r[r2] = al[r2] * l_r[r2] + e0 + e1;
      Pb[wave][(quad * 4 + r2) * 40 + lm]      = f2b(e0);
      Pb[wave][(quad * 4 + r2) * 40 + 16 + lm] = f2b(e1);
    }
#pragma unroll
    for (int dt = 0; dt < 12; ++dt) {
#pragma unroll
      for (int r2 = 0; r2 < 4; ++r2) oacc[dt][r2] *= al[r2];
    }

    short8 pf = *(const short8*)(&Pb[wave][lm * 40 + quad * 8]);
#pragma unroll
    for (int dt = 0; dt < 12; ++dt) {
      short8 vf = *(const short8*)(&Vb[cur][(dt * 64 + quad * 16 + lm) * 8]);
      oacc[dt] = __builtin_amdgcn_mfma_f32_16x16x32_bf16(pf, vf, oacc[dt], 0, 0, 0);
    }
    __syncthreads();
  }

#pragma unroll
  for (int r2 = 0; r2 < 4; ++r2) {
#pragma unroll
    for (int off = 1; off < 16; off <<= 1) l_r[r2] += __shfl_xor(l_r[r2], off, 64);
    l_r[r2] = 1.f / l_r[r2];
  }
  short* orow = o + (size_t)(b * T + q0 + wave * 16) * H_ + h * DH_;
#pragma unroll
  for (int dt = 0; dt < 12; ++dt) {
#pragma unroll
    for (int r2 = 0; r2 < 4; ++r2)
      orow[(size_t)(quad * 4 + r2) * H_ + dt * 16 + lm] = f2b(oacc[dt][r2] * l_r[r2]);
  }
}

// ============ LayerNorm (H=384), wave per row ============
__global__ __launch_bounds__(256) void ln_kernel(const float* __restrict__ X,
                                                 const float* __restrict__ sb,
                                                 float* __restrict__ Yf,
                                                 short* __restrict__ Yb, int M)
{
  int row  = blockIdx.x * 4 + (threadIdx.x >> 6);
  int lane = threadIdx.x & 63;
  const float* x = X + (size_t)row * H_;
  float v[6]; float s = 0.f, ss = 0.f;
#pragma unroll
  for (int i = 0; i < 6; ++i) { v[i] = x[lane + i * 64]; s += v[i]; ss += v[i] * v[i]; }
#pragma unroll
  for (int o = 32; o; o >>= 1) { s += __shfl_down(s, o, 64); ss += __shfl_down(ss, o, 64); }
  s = __shfl(s, 0, 64); ss = __shfl(ss, 0, 64);
  float mean = s * (1.0f / H_);
  float var  = ss * (1.0f / H_) - mean * mean;
  float r = rsqrtf(var + 1e-5f);
  float* yf = Yf + (size_t)row * H_;
#pragma unroll
  for (int i = 0; i < 6; ++i) {
    int c = lane + i * 64;
    float y = (v[i] - mean) * r * sb[c] + sb[H_ + c];
    yf[c] = y;
    if (Yb) Yb[(size_t)row * H_ + c] = f2b(y);
  }
}

// ============ length-pred GEMV ============
__global__ void gemv_kernel(const float* __restrict__ A, const float* __restrict__ w,
                            const float* __restrict__ bflt, float* __restrict__ out, int M)
{
  int row  = blockIdx.x * 4 + (threadIdx.x >> 6);
  int lane = threadIdx.x & 63;
  const float* a = A + (size_t)row * H_;
  float s = 0.f;
#pragma unroll
  for (int i = 0; i < 6; ++i) s += a[lane + i * 64] * w[lane + i * 64];
#pragma unroll
  for (int o = 32; o; o >>= 1) s += __shfl_down(s, o, 64);
  if (lane == 0) out[row] = s + bflt[0];
}

__global__ void cumsum_kernel(const int* __restrict__ al, int* __restrict__ cum) {
  int b = threadIdx.x;
  if (b < B_) {
    int acc = 0;
    for (int s = 0; s < S_; ++s) { acc += al[b * S_ + s]; cum[b * S_ + s] = acc; }
  }
}

__global__ void expand_kernel(const float* __restrict__ xe, const int* __restrict__ cum,
                              float* __restrict__ yf, short* __restrict__ yb) {
  int t = blockIdx.x, b = blockIdx.y;
  const int* c = cum + b * S_;
  int lo = 0, hi = S_;
  while (lo < hi) { int mid = (lo + hi) >> 1; if (c[mid] <= t) lo = mid + 1; else hi = mid; }
  int idx = lo < S_ ? lo : S_ - 1;
  bool valid = t < c[S_ - 1];
  const float* src = xe + ((size_t)b * S_ + idx) * H_;
  float* df = yf + ((size_t)b * TOUT_ + t) * H_;
  short* db = yb + ((size_t)b * TOUT_ + t) * H_;
  for (int i = threadIdx.x; i < H_; i += blockDim.x) {
    float v = (valid ? src[i] : 0.f) + pe_val(t, i);
    df[i] = v; db[i] = f2b(v);
  }
}

// ================= host orchestration =================
// mtw: 4 -> 128-row tile (wide-N GEMMs), 2 -> 64-row tile (N<=512 GEMMs)
static inline void gemm(const short* A, const short* Wt, const float* bias, const float* res,
                        float* Cf, short* Cb, const short* zbuf, int M, int N, int Kd, int T,
                        int ntaps, int mtw, int Nout, int flags, hipStream_t st) {
  int tm = mtw * 32;
  dim3 g((N + 127) / 128, M / tm);
  if (ntaps == 3) {
    if (mtw == 4)
      mfma_gemm<3,4><<<g, 256, 0, st>>>(A, Wt, bias, res, Cf, Cb, zbuf, M, N, Kd, T, Nout, flags);
    else
      mfma_gemm<3,2><<<g, 256, 0, st>>>(A, Wt, bias, res, Cf, Cb, zbuf, M, N, Kd, T, Nout, flags);
  } else {
    if (mtw == 4)
      mfma_gemm<1,4><<<g, 256, 0, st>>>(A, Wt, bias, res, Cf, Cb, zbuf, M, N, Kd, T, Nout, flags);
    else
      mfma_gemm<1,2><<<g, 256, 0, st>>>(A, Wt, bias, res, Cf, Cb, zbuf, M, N, Kd, T, Nout, flags);
  }
}

struct LayerW { const short *attn, *c1, *c2; const float *ab, *c1b, *c2b, *ln; };

static void fft_block(float* x, short* xb, short* qkvb, short* ob, short* vtb, short* h2b,
                      const short* zbuf, const LayerW& w, int T, hipStream_t st)
{
  int M = B_ * T;
  const size_t msz = (size_t)H_ * H_;
  gemm(xb, w.attn, w.ab, nullptr, nullptr, qkvb, zbuf, M, 1152, H_, T, 1, 4, 0,
       F_BIAS | F_STB, st);
  vtrans_kernel<<<dim3(T / 32, 12, B_), 256, 0, st>>>(qkvb, vtb, T);
  if (T == 256) attn_flash<256><<<dim3((256 / 64) * 32), 256, 0, st>>>(qkvb, vtb, ob);
  else          attn_flash<1024><<<dim3((1024 / 64) * 32), 256, 0, st>>>(qkvb, vtb, ob);
  gemm(ob, w.attn + 3 * msz, w.ab + 3 * H_, x, x, nullptr, zbuf, M, H_, H_, T, 1, 2, 0,
       F_BIAS | F_RES | F_STF, st);
  ln_kernel<<<M / 4, 256, 0, st>>>(x, w.ln, x, xb, M);
  gemm(xb, w.c1, w.c1b, nullptr, nullptr, h2b, zbuf, M, H2_, H_, T, 3, 4, 0,
       F_BIAS | F_RELU | F_STB, st);
  gemm(h2b, w.c2, w.c2b, x, x, nullptr, zbuf, M, H_, H2_, T, 3, 2, 0,
       F_BIAS | F_RES | F_STF, st);
  ln_kernel<<<M / 4, 256, 0, st>>>(x, w.ln + 2 * H_, x, xb, M);
}

extern "C" void kernel_launch(void* const* d_in, const int* in_sizes, int n_in,
                              void* d_out, int out_size, void* d_ws, size_t ws_size,
                              hipStream_t stream)
{
  (void)in_sizes; (void)n_in; (void)out_size; (void)ws_size;
  const int*   tokens      = (const int*)d_in[0];
  const int*   alignes     = (const int*)d_in[1];
  const float* tok_emb     = (const float*)d_in[2];
  const float* enc_attn_w  = (const float*)d_in[3];
  const float* enc_attn_b  = (const float*)d_in[4];
  const float* enc_conv1_w = (const float*)d_in[5];
  const float* enc_conv1_b = (const float*)d_in[6];
  const float* enc_conv2_w = (const float*)d_in[7];
  const float* enc_conv2_b = (const float*)d_in[8];
  const float* enc_ln      = (const float*)d_in[9];
  const float* dec_attn_w  = (const float*)d_in[10];
  const float* dec_attn_b  = (const float*)d_in[11];
  const float* dec_conv1_w = (const float*)d_in[12];
  const float* dec_conv1_b = (const float*)d_in[13];
  const float* dec_conv2_w = (const float*)d_in[14];
  const float* dec_conv2_b = (const float*)d_in[15];
  const float* dec_ln      = (const float*)d_in[16];
  const float* al_c1w      = (const float*)d_in[17];
  const float* al_c1b      = (const float*)d_in[18];
  const float* al_c2w      = (const float*)d_in[19];
  const float* al_c2b      = (const float*)d_in[20];
  const float* al_ln       = (const float*)d_in[21];
  const float* al_lin_w    = (const float*)d_in[22];
  const float* al_lin_b    = (const float*)d_in[23];
  const float* dec_lin_w   = (const float*)d_in[24];
  const float* dec_lin_b   = (const float*)d_in[25];

  char* base = (char*)d_ws;
  size_t off = 0;
  auto alloc = [&](size_t bytes) -> char* {
    char* p = base + off;
    off += (bytes + 255) & ~(size_t)255;
    return p;
  };
  const size_t ME = (size_t)B_ * S_;      // 4096
  const size_t MD = (size_t)B_ * TOUT_;   // 16384
  float* xe   = (float*)alloc(ME * H_ * 4);
  short* xeb  = (short*)alloc(ME * H_ * 2);
  float* xd   = (float*)alloc(MD * H_ * 4);
  short* xdb  = (short*)alloc(MD * H_ * 2);
  short* qkvb = (short*)alloc(MD * 1152 * 2);
  short* ob   = (short*)alloc(MD * H_ * 2);
  short* h2b  = (short*)alloc(MD * H2_ * 2);     // first 12.6MB doubles as vtb
  short* vtb  = h2b;
  short* wAt  = (short*)alloc((size_t)32 * H_ * H_ * 2);
  short* wAl  = (short*)alloc((size_t)6 * H_ * H_ * 2);
  short* wC1  = (short*)alloc((size_t)24 * H_ * H2_ * 2);
  short* wC2  = (short*)alloc((size_t)24 * H_ * H2_ * 2);
  short* wMel = (short*)alloc((size_t)128 * H_ * 2);
  int*   cum  = (int*)alloc(ME * 4);
  short* zbuf = (short*)alloc(256);
  float* alf  = xd;                // aligner scratch (xd/xdb free until expand)
  short* alb  = xdb;

  float* mel_out = (float*)d_out;
  float* len_out = mel_out + (size_t)B_ * MEL_ * TOUT_;

  hipMemsetAsync(zbuf, 0, 256, stream);

  // ---- weight prep ----
  wtrans_kernel<<<dim3(12, 12, 32), 256, 0, stream>>>(enc_attn_w, dec_attn_w, 16, H_, H_, wAt);
  wtrans_kernel<<<dim3(12, 12, 6),  256, 0, stream>>>(al_c1w, al_c2w, 3, H_, H_, wAl);
  wtrans_kernel<<<dim3(48, 12, 24), 256, 0, stream>>>(enc_conv1_w, dec_conv1_w, 12, H_, H2_, wC1);
  wtrans_kernel<<<dim3(12, 48, 24), 256, 0, stream>>>(enc_conv2_w, dec_conv2_w, 12, H2_, H_, wC2);
  melpad_kernel<<<dim3(128 * H_ / 256), 256, 0, stream>>>(dec_lin_w, wMel);

  // ---- encoder ----
  embed_kernel<<<dim3(B_ * S_), 128, 0, stream>>>(tokens, tok_emb, xe, xeb);
  for (int i = 0; i < L_; ++i) {
    LayerW w;
    w.attn = wAt + (size_t)i * 4 * H_ * H_;
    w.c1   = wC1 + (size_t)i * 3 * H_ * H2_;
    w.c2   = wC2 + (size_t)i * 3 * H_ * H2_;
    w.ab   = enc_attn_b + (size_t)i * 4 * H_;
    w.c1b  = enc_conv1_b + (size_t)i * H2_;
    w.c2b  = enc_conv2_b + (size_t)i * H_;
    w.ln   = enc_ln + (size_t)i * 4 * H_;
    fft_block(xe, xeb, qkvb, ob, vtb, h2b, zbuf, w, S_, stream);
  }

  // ---- aligner ----
  {
    int Ma = B_ * S_;
    gemm(xeb, wAl, al_c1b, nullptr, alf, nullptr, zbuf, Ma, H_, H_, S_, 3, 2, 0,
         F_BIAS | F_RELU | F_STF, stream);
    ln_kernel<<<Ma / 4, 256, 0, stream>>>(alf, al_ln, alf, alb, Ma);
    gemm(alb, wAl + (size_t)3 * H_ * H_, al_c2b, nullptr, alf, nullptr, zbuf, Ma, H_, H_, S_,
         3, 2, 0, F_BIAS | F_RELU | F_STF, stream);
    ln_kernel<<<Ma / 4, 256, 0, stream>>>(alf, al_ln + 2 * H_, alf, (short*)nullptr, Ma);
    gemv_kernel<<<Ma / 4, 256, 0, stream>>>(alf, al_lin_w, al_lin_b, len_out, Ma);
  }

  // ---- length regulator ----
  cumsum_kernel<<<1, 64, 0, stream>>>(alignes, cum);
  expand_kernel<<<dim3(TOUT_, B_), 128, 0, stream>>>(xe, cum, xd, xdb);

  // ---- decoder ----
  for (int i = 0; i < L_; ++i) {
    LayerW w;
    w.attn = wAt + (size_t)(16 + i * 4) * H_ * H_;
    w.c1   = wC1 + (size_t)(12 + i * 3) * H_ * H2_;
    w.c2   = wC2 + (size_t)(12 + i * 3) * H_ * H2_;
    w.ab   = dec_attn_b + (size_t)i * 4 * H_;
    w.c1b  = dec_conv1_b + (size_t)i * H2_;
    w.c2b  = dec_conv2_b + (size_t)i * H_;
    w.ln   = dec_ln + (size_t)i * 4 * H_;
    fft_block(xd, xdb, qkvb, ob, vtb, h2b, zbuf, w, TOUT_, stream);
  }

  // ---- final mel projection, transposed write [B, MEL, TOUT] ----
  gemm(xdb, wMel, dec_lin_b, nullptr, mel_out, nullptr, zbuf, B_ * TOUT_, 128, H_, TOUT_,
       1, 2, MEL_, F_BIAS | F_TRANS, stream);
}